// Round 1
// baseline (252.142 us; speedup 1.0000x reference)
//
#include <hip/hip_runtime.h>
#include <hip/hip_bf16.h>
#include <math.h>

typedef __attribute__((ext_vector_type(8))) short short8v;
typedef __attribute__((ext_vector_type(4))) short short4v;
typedef __attribute__((ext_vector_type(4))) float float4v;
typedef unsigned short u16;

#define BATCH 32768
#define PAGES 4096
#define QB 64
#define PT 64
#define NT (PAGES / PT)
#define QS_LD 136

__device__ __forceinline__ u16 f2bf(float f) {
  __hip_bfloat16 h = __float2bfloat16(f);
  union { __hip_bfloat16 h; u16 u; } cv; cv.h = h; return cv.u;
}
__device__ __forceinline__ float bf2f(u16 b) {
  union { u16 u; __hip_bfloat16 h; } cv; cv.u = b; return __bfloat162float(cv.h);
}
__device__ __forceinline__ float sigm(float x) { return 1.0f / (1.0f + __expf(-x)); }

// ---------------------------------------------------------------------------
// prep_k: build Kg [4096][128] bf16 with chunk XOR-swizzle baked in, + colbias.
// Logical dims: 0..63 = page_keys, 64..83 = hi(4*sigmoid(vp)), 84..103 = hi again,
// 104..123 = lo(4*sigmoid(vp)), 124..127 = 0.
// Chunk c (8 dims) stored at chunk position c ^ (p & 7)  (inverse == forward, XOR).
// cb[p] = -2 * sum(sigmoid(vp)^2)  (f32, exact path).
// ---------------------------------------------------------------------------
__global__ __launch_bounds__(256) void prep_k(const float* __restrict__ pk,
                                              const float* __restrict__ vp,
                                              u16* __restrict__ Kg,
                                              float* __restrict__ cbg) {
  int tg = blockIdx.x * 256 + threadIdx.x;   // 65536 threads: (page, chunk)
  int p = tg >> 4, c = tg & 15;
  short8v vals;
#pragma unroll
  for (int e = 0; e < 8; ++e) {
    int d = c * 8 + e;
    u16 bits;
    if (d < 64) {
      bits = f2bf(pk[p * 64 + d]);
    } else if (d < 124) {
      int j = (d - 64) % 20;
      float s4 = 4.0f * sigm(vp[p * 20 + j]);
      u16 hi = f2bf(s4);
      bits = (d < 104) ? hi : f2bf(s4 - bf2f(hi));
    } else {
      bits = 0;
    }
    vals[e] = (short)bits;
  }
  int cs = c ^ (p & 7);
  *reinterpret_cast<short8v*>(&Kg[p * 128 + cs * 8]) = vals;
  if (c == 0) {
    float s2 = 0.0f;
#pragma unroll
    for (int j = 0; j < 20; ++j) { float s = sigm(vp[p * 20 + j]); s2 += s * s; }
    cbg[p] = -2.0f * s2;
  }
}

// ---------------------------------------------------------------------------
// prep_v: Vt [32][4096] bf16, pre-transposed, pages permuted within each
// 64-tile: stored index s = (p&15)*4 + ((p>>4)&3) so that the packed P layout
// in LDS (Ps[q][li*4+ct]) and V agree on k-order inside the PV MFMA.
// vcol 0..19 = sigmoid(phys), 20..23 = sigmoid(perms), 24..31 = 0.
// ---------------------------------------------------------------------------
__global__ __launch_bounds__(256) void prep_v(const float* __restrict__ ph,
                                              const float* __restrict__ pr,
                                              u16* __restrict__ Vtg) {
  int tg = blockIdx.x * 256 + threadIdx.x;   // 131072 threads: (vcol, page)
  int p = tg & 4095, v = tg >> 12;
  float x;
  if (v < 20) x = sigm(ph[p * 20 + v]);
  else if (v < 24) x = sigm(pr[p * 4 + (v - 20)]);
  else x = 0.0f;
  int s = (p & 15) * 4 + ((p >> 4) & 3);
  Vtg[v * 4096 + (p & ~63) + s] = f2bf(x);
}

// ---------------------------------------------------------------------------
// main: 512 blocks x 256 threads, 64 queries/block, flash over 64-page tiles.
// ---------------------------------------------------------------------------
__global__ __launch_bounds__(256) void mmu_main(
    const float* __restrict__ vpb_g, const float* __restrict__ W1g,
    const float* __restrict__ b1g, const float* __restrict__ W2g,
    const float* __restrict__ b2g, const float* __restrict__ temp_g,
    const u16* __restrict__ Kg, const float* __restrict__ cbg,
    const u16* __restrict__ Vtg, float* __restrict__ outp) {
  __shared__ __align__(16) u16 Qs[QB * QS_LD];          // 17408 B
  __shared__ __align__(16) float vpb_s[QB * 20];        //  5120 B
  __shared__ __align__(16) char un[26624];              // union region
  float* W1s = (float*)un;                              // [20][128] (MLP)
  float* hs  = (float*)(un + 10240);                    // [32][128] (MLP)
  u16* Ks    = (u16*)un;                                // [64*128]  (main)
  u16* Ps    = (u16*)(un + 16384);                      // [4][16][72] (main)

  const int tid = threadIdx.x;
  const int q0 = blockIdx.x * QB;

  for (int i = tid; i < QB * 20; i += 256) vpb_s[i] = vpb_g[q0 * 20 + i];
  for (int i = tid; i < 20 * 128; i += 256) W1s[i] = W1g[i];
  __syncthreads();

  // Q cols 64..127: [vhi | vlo | vhi | 0] paired against K's [shi | shi | slo | 0]
  for (int i = tid; i < QB * 64; i += 256) {
    int q = i >> 6, c = 64 + (i & 63);
    u16 bits;
    if (c < 84) bits = f2bf(vpb_s[q * 20 + c - 64]);
    else if (c < 104) { float v = vpb_s[q * 20 + c - 84]; u16 hi = f2bf(v); bits = f2bf(v - bf2f(hi)); }
    else if (c < 124) bits = f2bf(vpb_s[q * 20 + c - 104]);
    else bits = 0;
    Qs[q * QS_LD + c] = bits;
  }

  // MLP: h = gelu_exact(vpb@W1+b1); query = h@W2+b2  (two 32-row halves)
  for (int half = 0; half < 2; ++half) {
    const int qb = half * 32;
    for (int i = tid; i < 32 * 128; i += 256) {
      int q = i >> 7, cc = i & 127;
      float acc = b1g[cc];
#pragma unroll
      for (int j = 0; j < 20; ++j) acc += vpb_s[(qb + q) * 20 + j] * W1s[j * 128 + cc];
      hs[i] = 0.5f * acc * (1.0f + erff(acc * 0.70710678118654752f));
    }
    __syncthreads();
    for (int i = tid; i < 32 * 64; i += 256) {
      int q = i >> 6, k = i & 63;
      float acc = b2g[k];
      for (int c = 0; c < 128; ++c) acc += hs[q * 128 + c] * W2g[c * 64 + k];
      Qs[(qb + q) * QS_LD + k] = f2bf(acc);
    }
    __syncthreads();
  }

  const int lane = tid & 63, w = tid >> 6, g = lane >> 4, li = lane & 15;
  const float invt = 1.0f / fmaxf(fabsf(temp_g[0]), 0.1f);
  const float c2 = invt * 1.4426950408889634f;   // log2(e)/temp

  // hoist Q A-frags (row = li -> query w*16+li, chunk = ks*4+g)
  short8v qf[4];
#pragma unroll
  for (int ks = 0; ks < 4; ++ks)
    qf[ks] = *reinterpret_cast<const short8v*>(&Qs[(w * 16 + li) * QS_LD + ks * 32 + g * 8]);

  float4v Ov0 = {0.f, 0.f, 0.f, 0.f}, Ov1 = {0.f, 0.f, 0.f, 0.f};
  float m_run[4] = {-1e30f, -1e30f, -1e30f, -1e30f};
  float lsum[4] = {0.f, 0.f, 0.f, 0.f};
  u16* Psw = Ps + w * (16 * 72);

  for (int t = 0; t < NT; ++t) {
    // stage K tile (reg-staged this round)
    const short8v* gsrc = reinterpret_cast<const short8v*>(Kg) + t * 1024;
    short8v s0 = gsrc[tid], s1 = gsrc[256 + tid], s2 = gsrc[512 + tid], s3 = gsrc[768 + tid];
    __syncthreads();
    short8v* kdst = reinterpret_cast<short8v*>(Ks);
    kdst[tid] = s0; kdst[256 + tid] = s1; kdst[512 + tid] = s2; kdst[768 + tid] = s3;
    __syncthreads();

    const int p0 = t * PT;
    float sv[4][4];
#pragma unroll
    for (int ct = 0; ct < 4; ++ct) {
      float4v acc = {0.f, 0.f, 0.f, 0.f};
      const int row = ct * 16 + li;
      const float cbv = cbg[p0 + row];
#pragma unroll
      for (int ks = 0; ks < 4; ++ks) {
        const int ch = (ks * 4 + g) ^ (row & 7);
        short8v b = *reinterpret_cast<const short8v*>(&Ks[row * 128 + ch * 8]);
        acc = __builtin_amdgcn_mfma_f32_16x16x32_bf16(qf[ks], b, acc, 0, 0, 0);
      }
#pragma unroll
      for (int r = 0; r < 4; ++r) sv[ct][r] = acc[r] + cbv;
    }

    // online softmax (wave-private; reduce over 16 page-lanes)
    float mt[4];
#pragma unroll
    for (int r = 0; r < 4; ++r)
      mt[r] = fmaxf(fmaxf(sv[0][r], sv[1][r]), fmaxf(sv[2][r], sv[3][r]));
#pragma unroll
    for (int msk = 1; msk <= 8; msk <<= 1) {
#pragma unroll
      for (int r = 0; r < 4; ++r) mt[r] = fmaxf(mt[r], __shfl_xor(mt[r], msk));
    }
    float fr[4];
#pragma unroll
    for (int r = 0; r < 4; ++r) {
      float mn = fmaxf(m_run[r], mt[r]);
      fr[r] = exp2f((m_run[r] - mn) * c2);
      m_run[r] = mn;
    }
#pragma unroll
    for (int r = 0; r < 4; ++r) {
      const float mc = m_run[r] * c2;
      float p0v = exp2f(sv[0][r] * c2 - mc);
      float p1v = exp2f(sv[1][r] * c2 - mc);
      float p2v = exp2f(sv[2][r] * c2 - mc);
      float p3v = exp2f(sv[3][r] * c2 - mc);
      lsum[r] = lsum[r] * fr[r] + ((p0v + p1v) + (p2v + p3v));
      short4v pb;
      pb[0] = (short)f2bf(p0v); pb[1] = (short)f2bf(p1v);
      pb[2] = (short)f2bf(p2v); pb[3] = (short)f2bf(p3v);
      *reinterpret_cast<short4v*>(&Psw[(g * 4 + r) * 72 + li * 4]) = pb;   // packed k-order
    }
#pragma unroll
    for (int r = 0; r < 4; ++r) { Ov0[r] *= fr[r]; Ov1[r] *= fr[r]; }

    // PV: A = packed P (wave-private LDS), B = pre-permuted V^T from global (L2)
#pragma unroll
    for (int ks2 = 0; ks2 < 2; ++ks2) {
      short8v a = *reinterpret_cast<const short8v*>(&Psw[li * 72 + ks2 * 32 + g * 8]);
      short8v b0 = *reinterpret_cast<const short8v*>(&Vtg[(li) * 4096 + p0 + ks2 * 32 + g * 8]);
      short8v b1v = *reinterpret_cast<const short8v*>(&Vtg[(16 + li) * 4096 + p0 + ks2 * 32 + g * 8]);
      Ov0 = __builtin_amdgcn_mfma_f32_16x16x32_bf16(a, b0, Ov0, 0, 0, 0);
      Ov1 = __builtin_amdgcn_mfma_f32_16x16x32_bf16(a, b1v, Ov1, 0, 0, 0);
    }
  }

  // final: reduce lsum across the 16 page-lanes, normalize, write out
#pragma unroll
  for (int msk = 1; msk <= 8; msk <<= 1) {
#pragma unroll
    for (int r = 0; r < 4; ++r) lsum[r] += __shfl_xor(lsum[r], msk);
  }
#pragma unroll
  for (int r = 0; r < 4; ++r) {
    const float inv = 1.0f / lsum[r];
    const int q = q0 + w * 16 + g * 4 + r;
    outp[q * 20 + li] = Ov0[r] * inv;            // vcols 0..15
    const int vc = 16 + li;
    const float v1 = Ov1[r] * inv;
    if (vc < 20) outp[q * 20 + vc] = v1;         // vcols 16..19
    else if (vc == 20) outp[BATCH * 20 + q] = v1;                 // perms[:,0]
    else if (vc < 24) outp[BATCH * 21 + q * 3 + (vc - 21)] = v1;  // perms[:,1:4]
  }
}

extern "C" void kernel_launch(void* const* d_in, const int* in_sizes, int n_in,
                              void* d_out, int out_size, void* d_ws, size_t ws_size,
                              hipStream_t stream) {
  const float* vpb = (const float*)d_in[0];
  const float* pk  = (const float*)d_in[1];
  const float* vp  = (const float*)d_in[2];
  const float* ph  = (const float*)d_in[3];
  const float* pr  = (const float*)d_in[4];
  const float* W1  = (const float*)d_in[5];
  const float* b1  = (const float*)d_in[6];
  const float* W2  = (const float*)d_in[7];
  const float* b2  = (const float*)d_in[8];
  const float* tp  = (const float*)d_in[9];

  u16* Kg    = (u16*)d_ws;                                        // 1,048,576 B
  float* cbg = (float*)((char*)d_ws + PAGES * 128 * 2);           //    16,384 B
  u16* Vtg   = (u16*)((char*)d_ws + PAGES * 128 * 2 + PAGES * 4); //   262,144 B
  float* outp = (float*)d_out;

  hipLaunchKernelGGL(prep_k, dim3(256), dim3(256), 0, stream, pk, vp, Kg, cbg);
  hipLaunchKernelGGL(prep_v, dim3(512), dim3(256), 0, stream, ph, pr, Vtg);
  hipLaunchKernelGGL(mmu_main, dim3(512), dim3(256), 0, stream,
                     vpb, W1, b1, W2, b2, tp, Kg, cbg, Vtg, outp);
}